// Round 4
// baseline (3060.494 us; speedup 1.0000x reference)
//
#include <hip/hip_runtime.h>
#include <math.h>

// Residual VQ: x (262144,128) fp32, codebooks (3,256,128) fp32.
// Output: [indices as float (262144*3)] ++ [quantized (262144*128)].
//
// ARITHMETIC CONTRACT (round 3, absmax=0 — do not change):
//   M_k  = OpenBLAS sgemm K-loop: sequential FMA chain j=0..127, acc init 0
//   A    = np.sum(r*r): pairwise_sum 8-accumulator scheme, products rounded
//          separately (fmaf(x,x,0) = single-rounded product, blocks fusion)
//   d2_k = (A - 2.0f*M_k) + B_k ; argmin strict < ascending k
//   residual -= q ; quantized = (q0 + q1) + q2  (elementwise fp32, ref order)
//
// ROUND 8 CHANGE: k-tiled GEMM structure, residual lives in LDS.
// r3..r7 all tried to make a 128-float residual register-resident; the RA
// spilled it every time (VGPR pinned at 104 across three source idioms).
// New structure needs only a small live set BY CONSTRUCTION:
//   - residual master copy in LDS (512B/thread row, 16B-chunk XOR swizzle
//     cj^(tid&7) -> wave ds_read_b128 at the structural 8-dword/bank floor)
//   - K_T=16 accumulator chains/tile: one 32-float LDS chunk feeds 16x32
//     FMAs (LDS pipe ~9% of VALU); chunks ping-pong prefetched (qa/qb/qc)
//   - codebook rows wave-uniform -> s_load to SGPRs (scalar pipe)
// Same arithmetic DAG (chain order j ascending per k, pairwise-8 A, strict-<
// ascending argmin) — only operand locations changed.
// LDS 64K+3K per 128-thread block -> 2 blocks/CU -> 1 wave/SIMD (intended:
// ILP + prefetch hide latency, not TLP).

constexpr int kItems = 262144;
constexpr int kDim   = 128;
constexpr int kNcb   = 3;
constexpr int kK     = 256;
constexpr int kBlock = 128;
constexpr int kKT    = 16;

__device__ __forceinline__ float sq_rn(float x) {
    return __builtin_fmaf(x, x, 0.0f);   // single-rounded product, blocks contraction
}

// pointer version — ONLY for codebook B_k staging (global reads, no alloca)
__device__ __forceinline__ float np_sumsq128(const float* __restrict__ p) {
    float a0 = sq_rn(p[0]), a1 = sq_rn(p[1]), a2 = sq_rn(p[2]), a3 = sq_rn(p[3]),
          a4 = sq_rn(p[4]), a5 = sq_rn(p[5]), a6 = sq_rn(p[6]), a7 = sq_rn(p[7]);
    #pragma unroll
    for (int i = 8; i < 128; i += 8) {
        a0 = a0 + sq_rn(p[i + 0]); a1 = a1 + sq_rn(p[i + 1]);
        a2 = a2 + sq_rn(p[i + 2]); a3 = a3 + sq_rn(p[i + 3]);
        a4 = a4 + sq_rn(p[i + 4]); a5 = a5 + sq_rn(p[i + 5]);
        a6 = a6 + sq_rn(p[i + 6]); a7 = a7 + sq_rn(p[i + 7]);
    }
    return ((a0 + a1) + (a2 + a3)) + ((a4 + a5) + (a6 + a7));
}

// ---- macros ---------------------------------------------------------------
// 4 FMAs of one float4 residual chunk-quarter into chain mk (j ascending)
#define FMAQ(mk, q, r_, o) \
  mk = __builtin_fmaf((q).x, (r_)[(o) + 0], mk); \
  mk = __builtin_fmaf((q).y, (r_)[(o) + 1], mk); \
  mk = __builtin_fmaf((q).z, (r_)[(o) + 2], mk); \
  mk = __builtin_fmaf((q).w, (r_)[(o) + 3], mk);

// one codebook row's 32-j chunk into chain mk; rp = cbase + kt*128 + jt*32
#define KROW(kk, mk, p, rp) { const float* r_ = (rp) + (size_t)(kk) * kDim; \
  FMAQ(mk, p##0, r_, 0)  FMAQ(mk, p##1, r_, 4)  FMAQ(mk, p##2, r_, 8)  FMAQ(mk, p##3, r_, 12) \
  FMAQ(mk, p##4, r_, 16) FMAQ(mk, p##5, r_, 20) FMAQ(mk, p##6, r_, 24) FMAQ(mk, p##7, r_, 28) }

#define K16(p, rp) \
  KROW(0,m0,p,rp)   KROW(1,m1,p,rp)   KROW(2,m2,p,rp)   KROW(3,m3,p,rp)   \
  KROW(4,m4,p,rp)   KROW(5,m5,p,rp)   KROW(6,m6,p,rp)   KROW(7,m7,p,rp)   \
  KROW(8,m8,p,rp)   KROW(9,m9,p,rp)   KROW(10,m10,p,rp) KROW(11,m11,p,rp) \
  KROW(12,m12,p,rp) KROW(13,m13,p,rp) KROW(14,m14,p,rp) KROW(15,m15,p,rp)

#define Q8DECL(p) float4 p##0, p##1, p##2, p##3, p##4, p##5, p##6, p##7;
// load 8 swizzled float4 chunks of this thread's residual row (j = jt*32..+31)
#define Q8LOAD(p, jt) \
  p##0 = rq[(((jt)*8 + 0) ^ t7)]; p##1 = rq[(((jt)*8 + 1) ^ t7)]; \
  p##2 = rq[(((jt)*8 + 2) ^ t7)]; p##3 = rq[(((jt)*8 + 3) ^ t7)]; \
  p##4 = rq[(((jt)*8 + 4) ^ t7)]; p##5 = rq[(((jt)*8 + 5) ^ t7)]; \
  p##6 = rq[(((jt)*8 + 6) ^ t7)]; p##7 = rq[(((jt)*8 + 7) ^ t7)];

// 2.0f*m exact (exponent bump) -> (A-2m)+B bit-safe fused or not
#define FIN1(kk, mk) { float t_ = (A - 2.0f * mk) + s_B[c * kK + kt + (kk)]; \
  if (t_ < best) { best = t_; bi = kt + (kk); } }
#define FIN16() \
  FIN1(0,m0)   FIN1(1,m1)   FIN1(2,m2)   FIN1(3,m3)   \
  FIN1(4,m4)   FIN1(5,m5)   FIN1(6,m6)   FIN1(7,m7)   \
  FIN1(8,m8)   FIN1(9,m9)   FIN1(10,m10) FIN1(11,m11) \
  FIN1(12,m12) FIN1(13,m13) FIN1(14,m14) FIN1(15,m15)

__global__ __launch_bounds__(kBlock, 2) void rvq_kernel(
    const float* __restrict__ x,
    const float* __restrict__ cb,
    float* __restrict__ out)
{
    __shared__ float  s_B[kNcb * kK];                 // 3 KiB
    __shared__ float4 s_r4[kBlock * (kDim / 4)];      // 64 KiB swizzled residual

    // B_k = np.sum(cb*cb, axis=-1), bit-exact
    for (int m = threadIdx.x; m < kNcb * kK; m += kBlock)
        s_B[m] = np_sumsq128(cb + (size_t)m * kDim);
    __syncthreads();

    const int tid = threadIdx.x;
    const int t7  = tid & 7;
    float4* __restrict__ rq = s_r4 + tid * (kDim / 4);   // this thread's row
    const int item = blockIdx.x * kBlock + tid;

    // ---- init: residual = x (swizzled into LDS); A = sum(x*x) pairwise-8
    float aa0=0.f,aa1=0.f,aa2=0.f,aa3=0.f,aa4=0.f,aa5=0.f,aa6=0.f,aa7=0.f;
    const float4* xv = (const float4*)(x + (size_t)item * kDim);
    #pragma unroll
    for (int cj = 0; cj < 32; ++cj) {       // term j=4cj+e -> acc (j&7), j asc
        float4 v = xv[cj];
        rq[cj ^ t7] = v;
        if (cj & 1) { aa4 += sq_rn(v.x); aa5 += sq_rn(v.y); aa6 += sq_rn(v.z); aa7 += sq_rn(v.w); }
        else        { aa0 += sq_rn(v.x); aa1 += sq_rn(v.y); aa2 += sq_rn(v.z); aa3 += sq_rn(v.w); }
    }
    float A = ((aa0 + aa1) + (aa2 + aa3)) + ((aa4 + aa5) + (aa6 + aa7));

    int sel0 = 0, sel1 = 0, sel2 = 0;

    #pragma unroll
    for (int c = 0; c < kNcb; ++c) {
        const float* __restrict__ cbase = cb + (size_t)c * kK * kDim;
        float best = INFINITY;
        int bi = 0;

        Q8DECL(qa) Q8DECL(qb) Q8DECL(qc)
        Q8LOAD(qa, 0)                       // jt=0 chunks persist across kt
        #pragma unroll 1
        for (int kt = 0; kt < kK; kt += kKT) {
            float m0=0.f,m1=0.f,m2=0.f,m3=0.f,m4=0.f,m5=0.f,m6=0.f,m7=0.f,
                  m8=0.f,m9=0.f,m10=0.f,m11=0.f,m12=0.f,m13=0.f,m14=0.f,m15=0.f;
            const float* rp0 = cbase + (size_t)kt * kDim;
            Q8LOAD(qb, 1)                   // prefetch jt=1 under K16(qa)
            K16(qa, rp0)
            Q8LOAD(qc, 2)                   // prefetch jt=2 under K16(qb)
            K16(qb, rp0 + 32)
            Q8LOAD(qb, 3)                   // prefetch jt=3 under K16(qc)
            K16(qc, rp0 + 64)
            K16(qb, rp0 + 96)
            FIN16()                         // ascending k, strict <
        }

        if (c == 0) sel0 = bi; else if (c == 1) sel1 = bi; else sel2 = bi;

        if (c < kNcb - 1) {                 // residual -= q; A for next stage
            const float* cw = cbase + (size_t)bi * kDim;   // divergent gather
            aa0=0.f;aa1=0.f;aa2=0.f;aa3=0.f;aa4=0.f;aa5=0.f;aa6=0.f;aa7=0.f;
            #pragma unroll
            for (int cj = 0; cj < 32; ++cj) {
                float4 rv = rq[cj ^ t7];
                float4 qv = *(const float4*)(cw + cj * 4);
                rv.x -= qv.x; rv.y -= qv.y; rv.z -= qv.z; rv.w -= qv.w;   // ref order
                rq[cj ^ t7] = rv;
                if (cj & 1) { aa4 += sq_rn(rv.x); aa5 += sq_rn(rv.y); aa6 += sq_rn(rv.z); aa7 += sq_rn(rv.w); }
                else        { aa0 += sq_rn(rv.x); aa1 += sq_rn(rv.y); aa2 += sq_rn(rv.z); aa3 += sq_rn(rv.w); }
            }
            A = ((aa0 + aa1) + (aa2 + aa3)) + ((aa4 + aa5) + (aa6 + aa7));
        }
    }

    // ---- outputs
    float* out_idx = out;                             // (items, 3) as float
    float* out_q   = out + (size_t)kItems * kNcb;     // (items, 128)
    out_idx[(size_t)item * kNcb + 0] = (float)sel0;
    out_idx[(size_t)item * kNcb + 1] = (float)sel1;
    out_idx[(size_t)item * kNcb + 2] = (float)sel2;

    const float* q0 = cb + ((size_t)0 * kK + sel0) * kDim;
    const float* q1 = cb + ((size_t)1 * kK + sel1) * kDim;
    const float* q2 = cb + ((size_t)2 * kK + sel2) * kDim;
    float* qo = out_q + (size_t)item * kDim;
    #pragma unroll
    for (int i = 0; i < kDim / 4; ++i) {
        float4 v0 = ((const float4*)q0)[i];
        float4 v1 = ((const float4*)q1)[i];
        float4 v2 = ((const float4*)q2)[i];
        float4 w;
        w.x = (v0.x + v1.x) + v2.x;
        w.y = (v0.y + v1.y) + v2.y;
        w.z = (v0.z + v1.z) + v2.z;
        w.w = (v0.w + v1.w) + v2.w;   // ((0+q0)+q1)+q2 in fp32, ref order
        ((float4*)qo)[i] = w;
    }
}

extern "C" void kernel_launch(void* const* d_in, const int* in_sizes, int n_in,
                              void* d_out, int out_size, void* d_ws, size_t ws_size,
                              hipStream_t stream) {
    const float* x  = (const float*)d_in[0];
    const float* cb = (const float*)d_in[1];
    float* out = (float*)d_out;
    rvq_kernel<<<kItems / kBlock, kBlock, 0, stream>>>(x, cb, out);
}